// Round 1
// baseline (610.166 us; speedup 1.0000x reference)
//
#include <hip/hip_runtime.h>

typedef __bf16 bfrag __attribute__((ext_vector_type(8)));
typedef float f32x4 __attribute__((ext_vector_type(4)));

__device__ __forceinline__ unsigned short f2bf(float f) {
  unsigned u = __float_as_uint(f);
  u = (u + 0x7fffu + ((u >> 16) & 1u)) >> 16;
  return (unsigned short)u;
}
__device__ __forceinline__ float bf2f(unsigned short u) {
  return __uint_as_float(((unsigned)u) << 16);
}

#define LDK 72  // 64 + 8 pad (ushorts) -> 2-way LDS bank aliasing only (free)

// ---------------- weight prep ----------------
// Wcat: rows 0..383 = in_proj_w (bf16)
// W2cat: 128 rows x 256 cols: [W2 = conv_w01 @ out_proj_w | W00 = conv_w[:,:,0,0]]
// cvec = conv_b + conv_w01 @ out_proj_b
__global__ void k_prep(const float* __restrict__ in_proj_w,
                       const float* __restrict__ conv_w,
                       const float* __restrict__ out_proj_w,
                       const float* __restrict__ out_proj_b,
                       const float* __restrict__ conv_b,
                       unsigned short* __restrict__ Wcat,
                       unsigned short* __restrict__ W2cat,
                       float* __restrict__ cvec) {
  int b = blockIdx.x, t = threadIdx.x;
  if (b < 384) {
    Wcat[b * 128 + t] = f2bf(in_proj_w[b * 128 + t]);
  } else {
    int c = b - 384;
    float s = 0.f;
    for (int k = 0; k < 128; ++k)
      s += conv_w[(c * 128 + k) * 2 + 1] * out_proj_w[k * 128 + t];
    W2cat[c * 256 + t] = f2bf(s);
    W2cat[c * 256 + 128 + t] = f2bf(conv_w[(c * 128 + t) * 2]);
    if (t == 0) {
      float cs = conv_b[c];
      for (int k = 0; k < 128; ++k)
        cs += conv_w[(c * 128 + k) * 2 + 1] * out_proj_b[k];
      cvec[c] = cs;
    }
  }
}

// ---------------- GEMM1: Q/K/V = x @ Wcat[cb]^T + b ----------------
// grid = (3, mtiles); block computes 128 rows x 128 cols, K=128 in 2 staged halves.
__global__ __launch_bounds__(256) void k_gemm_qkv(
    const float* __restrict__ x, const unsigned short* __restrict__ Wcat,
    const float* __restrict__ in_proj_b, unsigned short* __restrict__ Qb,
    unsigned short* __restrict__ Kb, unsigned short* __restrict__ Vb, int M) {
  __shared__ unsigned short sa[128 * LDK];
  __shared__ unsigned short sb[128 * LDK];
  const int cb = blockIdx.x;            // 0=Q 1=K 2=V
  const int m0 = blockIdx.y * 128;
  const int t = threadIdx.x;
  const int w = t >> 6, lane = t & 63, quad = lane >> 4, mr = lane & 15;

  f32x4 acc[2][8];
#pragma unroll
  for (int r = 0; r < 2; ++r)
#pragma unroll
    for (int c = 0; c < 8; ++c) acc[r][c] = (f32x4){0.f, 0.f, 0.f, 0.f};

  for (int kh = 0; kh < 2; ++kh) {
    // stage A: x rows m0..+128, cols kh*64..+64, fp32 -> bf16
#pragma unroll
    for (int i = 0; i < 8; ++i) {
      int ch = t + 256 * i;              // 2048 float4 chunks
      int row = ch >> 4, col4 = ch & 15;
      float4 v = make_float4(0.f, 0.f, 0.f, 0.f);
      if (m0 + row < M)
        v = *reinterpret_cast<const float4*>(&x[(size_t)(m0 + row) * 128 + kh * 64 + col4 * 4]);
      union { unsigned short s[4]; uint2 u; } p;
      p.s[0] = f2bf(v.x); p.s[1] = f2bf(v.y); p.s[2] = f2bf(v.z); p.s[3] = f2bf(v.w);
      *reinterpret_cast<uint2*>(&sa[row * LDK + col4 * 4]) = p.u;
    }
    // stage B: Wcat rows cb*128..+128, cols kh*64..+64 (bf16)
#pragma unroll
    for (int i = 0; i < 4; ++i) {
      int ch = t + 256 * i;              // 1024 chunks of 8 ushorts
      int row = ch >> 3, col8 = ch & 7;
      uint4 v = *reinterpret_cast<const uint4*>(
          &Wcat[(size_t)(cb * 128 + row) * 128 + kh * 64 + col8 * 8]);
      *reinterpret_cast<uint4*>(&sb[row * LDK + col8 * 8]) = v;
    }
    __syncthreads();
#pragma unroll
    for (int ks = 0; ks < 2; ++ks) {
      int k0 = ks * 32 + quad * 8;
      bfrag a0 = *reinterpret_cast<const bfrag*>(&sa[(w * 32 + mr) * LDK + k0]);
      bfrag a1 = *reinterpret_cast<const bfrag*>(&sa[(w * 32 + 16 + mr) * LDK + k0]);
#pragma unroll
      for (int c = 0; c < 8; ++c) {
        bfrag b = *reinterpret_cast<const bfrag*>(&sb[(c * 16 + mr) * LDK + k0]);
        acc[0][c] = __builtin_amdgcn_mfma_f32_16x16x32_bf16(a0, b, acc[0][c], 0, 0, 0);
        acc[1][c] = __builtin_amdgcn_mfma_f32_16x16x32_bf16(a1, b, acc[1][c], 0, 0, 0);
      }
    }
    __syncthreads();
  }
  unsigned short* dst = (cb == 0) ? Qb : (cb == 1) ? Kb : Vb;
  const float* bias = in_proj_b + cb * 128;
#pragma unroll
  for (int r = 0; r < 2; ++r) {
    int rowbase = m0 + w * 32 + r * 16 + quad * 4;
#pragma unroll
    for (int c = 0; c < 8; ++c) {
      int col = c * 16 + mr;
      float bv = bias[col];
#pragma unroll
      for (int g = 0; g < 4; ++g) {
        int row = rowbase + g;
        if (row < M) dst[(size_t)row * 128 + col] = f2bf(acc[r][c][g] + bv);
      }
    }
  }
}

// ---------------- attention: 1 wave per row ----------------
// lane l <-> channels {2l, 2l+1}; head = l>>4; 16-lane shfl reduce per head dot.
__global__ __launch_bounds__(256) void k_attn(
    const unsigned short* __restrict__ Qb, const unsigned short* __restrict__ Kb,
    const unsigned short* __restrict__ Vb, const int* __restrict__ fn,
    unsigned short* __restrict__ Ob, int M) {
  int w = threadIdx.x >> 6, lane = threadIdx.x & 63;
  int n = blockIdx.x * 4 + w;
  if (n >= M) return;
  const float scale = 0.17677669529663687f;  // 1/sqrt(32)
  ushort2 qp = *reinterpret_cast<const ushort2*>(&Qb[(size_t)n * 128 + 2 * lane]);
  float q0 = bf2f(qp.x), q1 = bf2f(qp.y);
  float v0[8], v1[8], s[8];
#pragma unroll
  for (int j = 0; j < 8; ++j) {
    int idx = fn[n * 9 + 1 + j];
    bool pad = (idx >= M);
    float k0 = 0.f, k1 = 0.f, a0 = 0.f, a1 = 0.f;
    if (!pad) {
      ushort2 kp = *reinterpret_cast<const ushort2*>(&Kb[(size_t)idx * 128 + 2 * lane]);
      ushort2 vp = *reinterpret_cast<const ushort2*>(&Vb[(size_t)idx * 128 + 2 * lane]);
      k0 = bf2f(kp.x); k1 = bf2f(kp.y);
      a0 = bf2f(vp.x); a1 = bf2f(vp.y);
    }
    v0[j] = a0; v1[j] = a1;
    float p = q0 * k0 + q1 * k1;
    p += __shfl_xor(p, 1);
    p += __shfl_xor(p, 2);
    p += __shfl_xor(p, 4);
    p += __shfl_xor(p, 8);
    s[j] = pad ? -1e30f : p * scale;
  }
  float m = s[0];
#pragma unroll
  for (int j = 1; j < 8; ++j) m = fmaxf(m, s[j]);
  float e[8], sum = 0.f;
#pragma unroll
  for (int j = 0; j < 8; ++j) { e[j] = __expf(s[j] - m); sum += e[j]; }
  float inv = 1.f / sum;
  float o0 = 0.f, o1 = 0.f;
#pragma unroll
  for (int j = 0; j < 8; ++j) { o0 += e[j] * v0[j]; o1 += e[j] * v1[j]; }
  o0 *= inv; o1 *= inv;
  ushort2 op; op.x = f2bf(o0); op.y = f2bf(o1);
  *reinterpret_cast<ushort2*>(&Ob[(size_t)n * 128 + 2 * lane]) = op;
}

// ---------------- GEMM2: out = [O | x] @ [W2 | W00]^T + cvec ----------------
__global__ __launch_bounds__(256) void k_gemm_out(
    const unsigned short* __restrict__ Ob, const float* __restrict__ x,
    const unsigned short* __restrict__ W2cat, const float* __restrict__ cvec,
    float* __restrict__ out, int M) {
  __shared__ unsigned short sa[128 * LDK];
  __shared__ unsigned short sb[128 * LDK];
  const int m0 = blockIdx.x * 128;
  const int t = threadIdx.x;
  const int w = t >> 6, lane = t & 63, quad = lane >> 4, mr = lane & 15;

  f32x4 acc[2][8];
#pragma unroll
  for (int r = 0; r < 2; ++r)
#pragma unroll
    for (int c = 0; c < 8; ++c) acc[r][c] = (f32x4){0.f, 0.f, 0.f, 0.f};

  for (int kc = 0; kc < 4; ++kc) {
    if (kc < 2) {  // A-chunk from Ob (bf16)
#pragma unroll
      for (int i = 0; i < 4; ++i) {
        int ch = t + 256 * i;
        int row = ch >> 3, col8 = ch & 7;
        uint4 v = {0u, 0u, 0u, 0u};
        if (m0 + row < M)
          v = *reinterpret_cast<const uint4*>(&Ob[(size_t)(m0 + row) * 128 + kc * 64 + col8 * 8]);
        *reinterpret_cast<uint4*>(&sa[row * LDK + col8 * 8]) = v;
      }
    } else {       // A-chunk from x (fp32 -> bf16)
#pragma unroll
      for (int i = 0; i < 8; ++i) {
        int ch = t + 256 * i;
        int row = ch >> 4, col4 = ch & 15;
        float4 v = make_float4(0.f, 0.f, 0.f, 0.f);
        if (m0 + row < M)
          v = *reinterpret_cast<const float4*>(&x[(size_t)(m0 + row) * 128 + (kc - 2) * 64 + col4 * 4]);
        union { unsigned short s[4]; uint2 u; } p;
        p.s[0] = f2bf(v.x); p.s[1] = f2bf(v.y); p.s[2] = f2bf(v.z); p.s[3] = f2bf(v.w);
        *reinterpret_cast<uint2*>(&sa[row * LDK + col4 * 4]) = p.u;
      }
    }
    // B: W2cat rows 0..128 (row stride 256), cols kc*64..+64
#pragma unroll
    for (int i = 0; i < 4; ++i) {
      int ch = t + 256 * i;
      int row = ch >> 3, col8 = ch & 7;
      uint4 v = *reinterpret_cast<const uint4*>(&W2cat[(size_t)row * 256 + kc * 64 + col8 * 8]);
      *reinterpret_cast<uint4*>(&sb[row * LDK + col8 * 8]) = v;
    }
    __syncthreads();
#pragma unroll
    for (int ks = 0; ks < 2; ++ks) {
      int k0 = ks * 32 + quad * 8;
      bfrag a0 = *reinterpret_cast<const bfrag*>(&sa[(w * 32 + mr) * LDK + k0]);
      bfrag a1 = *reinterpret_cast<const bfrag*>(&sa[(w * 32 + 16 + mr) * LDK + k0]);
#pragma unroll
      for (int c = 0; c < 8; ++c) {
        bfrag b = *reinterpret_cast<const bfrag*>(&sb[(c * 16 + mr) * LDK + k0]);
        acc[0][c] = __builtin_amdgcn_mfma_f32_16x16x32_bf16(a0, b, acc[0][c], 0, 0, 0);
        acc[1][c] = __builtin_amdgcn_mfma_f32_16x16x32_bf16(a1, b, acc[1][c], 0, 0, 0);
      }
    }
    __syncthreads();
  }
#pragma unroll
  for (int r = 0; r < 2; ++r) {
    int rowbase = m0 + w * 32 + r * 16 + quad * 4;
#pragma unroll
    for (int c = 0; c < 8; ++c) {
      int col = c * 16 + mr;
      float cv = cvec[col];
#pragma unroll
      for (int g = 0; g < 4; ++g) {
        int row = rowbase + g;
        if (row < M) out[(size_t)row * 128 + col] = acc[r][c][g] + cv;
      }
    }
  }
}

extern "C" void kernel_launch(void* const* d_in, const int* in_sizes, int n_in,
                              void* d_out, int out_size, void* d_ws, size_t ws_size,
                              hipStream_t stream) {
  const float* x          = (const float*)d_in[0];
  const int*   fn         = (const int*)d_in[1];
  // d_in[2] face_is_pad, d_in[3] pad_size: unused (pad <=> idx >= N per setup)
  const float* in_proj_w  = (const float*)d_in[4];
  const float* in_proj_b  = (const float*)d_in[5];
  const float* out_proj_w = (const float*)d_in[6];
  const float* out_proj_b = (const float*)d_in[7];
  const float* conv_w     = (const float*)d_in[8];
  const float* conv_b     = (const float*)d_in[9];
  const int M = in_sizes[0] / 128;

  // Q,K (bf16) live inside d_out: dead before k_gemm_out overwrites it with fp32 out.
  unsigned short* Qb = (unsigned short*)d_out;
  unsigned short* Kb = Qb + (size_t)M * 128;
  char* ws = (char*)d_ws;
  unsigned short* Vb    = (unsigned short*)ws;
  unsigned short* Ob    = (unsigned short*)(ws + (size_t)M * 128 * 2);
  unsigned short* Wcat  = (unsigned short*)(ws + (size_t)M * 128 * 4);
  unsigned short* W2cat = Wcat + 384 * 128;
  float*          cvec  = (float*)(W2cat + 128 * 256);

  const int mt = (M + 127) / 128;
  k_prep<<<dim3(512), dim3(128), 0, stream>>>(in_proj_w, conv_w, out_proj_w,
                                              out_proj_b, conv_b, Wcat, W2cat, cvec);
  k_gemm_qkv<<<dim3(3, mt), dim3(256), 0, stream>>>(x, Wcat, in_proj_b, Qb, Kb, Vb, M);
  k_attn<<<dim3((M + 3) / 4), dim3(256), 0, stream>>>(Qb, Kb, Vb, fn, Ob, M);
  k_gemm_out<<<dim3(mt), dim3(256), 0, stream>>>(Ob, x, W2cat, cvec, (float*)d_out, M);
}

// Round 4
// 471.848 us; speedup vs baseline: 1.2931x; 1.2931x over previous
//
#include <hip/hip_runtime.h>

typedef __bf16 bfrag __attribute__((ext_vector_type(8)));
typedef float f32x4 __attribute__((ext_vector_type(4)));

__device__ __forceinline__ unsigned short f2bf(float f) {
  unsigned u = __float_as_uint(f);
  u = (u + 0x7fffu + ((u >> 16) & 1u)) >> 16;
  return (unsigned short)u;
}
__device__ __forceinline__ float bflo(unsigned u) {  // low 16 bits -> float
  return __uint_as_float(u << 16);
}
__device__ __forceinline__ float bfhi(unsigned u) {  // high 16 bits -> float
  return __uint_as_float(u & 0xffff0000u);
}

#define LDA 136  // A-tile row stride (ushort): 128 + 8 pad (272B/row, 16B-aligned)
#define LDB 72   // B-tile row stride (ushort): 64 + 8 pad
#define LDT 136  // transpose-epilogue stride: rows stay 16B-aligned for ds_read_b128
#define LDK 72   // GEMM2 strides

// ---------------- weight prep ----------------
// Wcat rows 0..383 = in_proj_w (bf16)
// W2cat: 128 x 256: [W2 = conv_w01 @ out_proj_w | W00 = conv_w[:,:,0,0]]
// cvec = conv_b + conv_w01 @ out_proj_b
__global__ void k_prep(const float* __restrict__ in_proj_w,
                       const float* __restrict__ conv_w,
                       const float* __restrict__ out_proj_w,
                       const float* __restrict__ out_proj_b,
                       const float* __restrict__ conv_b,
                       unsigned short* __restrict__ Wcat,
                       unsigned short* __restrict__ W2cat,
                       float* __restrict__ cvec) {
  int b = blockIdx.x, t = threadIdx.x;
  if (b < 384) {
    Wcat[b * 128 + t] = f2bf(in_proj_w[b * 128 + t]);
  } else {
    int c = b - 384;
    float s = 0.f;
    for (int k = 0; k < 128; ++k)
      s += conv_w[(c * 128 + k) * 2 + 1] * out_proj_w[k * 128 + t];
    W2cat[c * 256 + t] = f2bf(s);
    W2cat[c * 256 + 128 + t] = f2bf(conv_w[(c * 128 + t) * 2]);
    if (t == 0) {
      float cs = conv_b[c];
      for (int k = 0; k < 128; ++k)
        cs += conv_w[(c * 128 + k) * 2 + 1] * out_proj_b[k];
      cvec[c] = cs;
    }
  }
}

// ---------------- fused QKV GEMM: x staged ONCE, loop over 3 weight blocks --
// Q -> Qb (row=128 ushort). K,V -> KVb interleaved (row=256 ushort: K|V).
__global__ __launch_bounds__(256) void k_gemm_qkv(
    const float* __restrict__ x, const unsigned short* __restrict__ Wcat,
    const float* __restrict__ in_proj_b, unsigned short* __restrict__ Qb,
    unsigned short* __restrict__ KVb, int M) {
  __shared__ unsigned short sa[128 * LDA];  // 34.8 KB (also reused for epilogue)
  __shared__ unsigned short sb[128 * LDB];  // 18.4 KB
  const int m0 = blockIdx.x * 128;
  const int t = threadIdx.x;
  const int w = t >> 6, lane = t & 63, quad = lane >> 4, mr = lane & 15;

  // stage A: full 128x128 x-tile, fp32 -> bf16
#pragma unroll
  for (int i = 0; i < 16; ++i) {
    int ch = t + 256 * i;  // 4096 float4 chunks: 128 rows x 32 col4
    int row = ch >> 5, col4 = ch & 31;
    float4 v = make_float4(0.f, 0.f, 0.f, 0.f);
    if (m0 + row < M)
      v = *reinterpret_cast<const float4*>(&x[(size_t)(m0 + row) * 128 + col4 * 4]);
    union { unsigned short s[4]; uint2 u; } p;
    p.s[0] = f2bf(v.x); p.s[1] = f2bf(v.y); p.s[2] = f2bf(v.z); p.s[3] = f2bf(v.w);
    *reinterpret_cast<uint2*>(&sa[row * LDA + col4 * 4]) = p.u;
  }
  __syncthreads();
  // hoist A fragments to registers (full K=128): af[ks][r]
  bfrag af[4][2];
#pragma unroll
  for (int ks = 0; ks < 4; ++ks) {
    int k0 = ks * 32 + quad * 8;
    af[ks][0] = *reinterpret_cast<const bfrag*>(&sa[(w * 32 + mr) * LDA + k0]);
    af[ks][1] = *reinterpret_cast<const bfrag*>(&sa[(w * 32 + 16 + mr) * LDA + k0]);
  }

#pragma unroll
  for (int cb = 0; cb < 3; ++cb) {
    f32x4 acc[2][8];
#pragma unroll
    for (int r = 0; r < 2; ++r)
#pragma unroll
      for (int c = 0; c < 8; ++c) acc[r][c] = (f32x4){0.f, 0.f, 0.f, 0.f};

#pragma unroll
    for (int kh = 0; kh < 2; ++kh) {
      __syncthreads();  // protect sb (and sa in epilogue) from previous phase
#pragma unroll
      for (int i = 0; i < 4; ++i) {
        int ch = t + 256 * i;  // 1024 chunks of 8 ushorts: 128 rows x 64 cols
        int row = ch >> 3, col8 = ch & 7;
        uint4 v = *reinterpret_cast<const uint4*>(
            &Wcat[(size_t)(cb * 128 + row) * 128 + kh * 64 + col8 * 8]);
        *reinterpret_cast<uint4*>(&sb[row * LDB + col8 * 8]) = v;
      }
      __syncthreads();
#pragma unroll
      for (int ks2 = 0; ks2 < 2; ++ks2) {
        int ks = kh * 2 + ks2;
        int k0 = ks2 * 32 + quad * 8;
#pragma unroll
        for (int c = 0; c < 8; ++c) {
          bfrag b = *reinterpret_cast<const bfrag*>(&sb[(c * 16 + mr) * LDB + k0]);
          acc[0][c] = __builtin_amdgcn_mfma_f32_16x16x32_bf16(af[ks][0], b, acc[0][c], 0, 0, 0);
          acc[1][c] = __builtin_amdgcn_mfma_f32_16x16x32_bf16(af[ks][1], b, acc[1][c], 0, 0, 0);
        }
      }
    }
    // epilogue: acc(+bias) -> sa (bf16, LDT stride) -> coalesced global stores
    const float* bias = in_proj_b + cb * 128;
    __syncthreads();  // everyone done with this cb's MFMAs (sb); sa free (af in regs)
#pragma unroll
    for (int r = 0; r < 2; ++r)
#pragma unroll
      for (int c = 0; c < 8; ++c) {
        int col = c * 16 + mr;
        float bv = bias[col];
#pragma unroll
        for (int g = 0; g < 4; ++g) {
          int row = w * 32 + r * 16 + quad * 4 + g;
          sa[row * LDT + col] = f2bf(acc[r][c][g] + bv);
        }
      }
    __syncthreads();
    unsigned short* dst = (cb == 0) ? Qb : KVb;
    const int ldst = (cb == 0) ? 128 : 256;
    const int cb_off = (cb == 2) ? 128 : 0;
    // FULL 128x128 tile: 2048 chunks of 8 ushorts (was 1024 -> dropped cols 64..127!)
#pragma unroll
    for (int i = 0; i < 8; ++i) {
      int ch = t + 256 * i;  // 2048 chunks: 128 rows x 16 col8
      int row = ch >> 4, col8 = ch & 15;
      if (m0 + row < M) {
        uint4 v = *reinterpret_cast<const uint4*>(&sa[row * LDT + col8 * 8]);
        *reinterpret_cast<uint4*>(&dst[(size_t)(m0 + row) * ldst + cb_off + col8 * 8]) = v;
      }
    }
  }
}

// ---------------- attention: 1 wave per row, interleaved KV gather ----------
// KV row = 512B: lanes 0..31 hold K ch 4*l5.., lanes 32..63 hold V ch 4*l5..
__global__ __launch_bounds__(256) void k_attn(
    const unsigned short* __restrict__ Qb, const unsigned short* __restrict__ KVb,
    const int* __restrict__ fn, unsigned short* __restrict__ Ob, int M) {
  int w = threadIdx.x >> 6, lane = threadIdx.x & 63;
  int n = blockIdx.x * 4 + w;
  if (n >= M) return;
  const float scale = 0.17677669529663687f;  // 1/sqrt(32)
  const int l5 = lane & 31;
  uint2 qp = *reinterpret_cast<const uint2*>(&Qb[(size_t)n * 128 + 4 * l5]);
  float q0 = bflo(qp.x), q1 = bfhi(qp.x), q2 = bflo(qp.y), q3 = bfhi(qp.y);
  int idx[8];
#pragma unroll
  for (int j = 0; j < 8; ++j) idx[j] = fn[n * 9 + 1 + j];
  float o0 = 0.f, o1 = 0.f, o2 = 0.f, o3 = 0.f, sum = 0.f;
#pragma unroll
  for (int j = 0; j < 8; ++j) {
    bool valid = idx[j] < M;
    int id = valid ? idx[j] : 0;
    uint2 kv = *reinterpret_cast<const uint2*>(&KVb[(size_t)id * 256 + 4 * lane]);
    float a0 = bflo(kv.x), a1 = bfhi(kv.x), a2 = bflo(kv.y), a3 = bfhi(kv.y);
    // lanes 0..31: partial q.k over this lane's 4 channels
    float p = q0 * a0 + q1 * a1 + q2 * a2 + q3 * a3;
    p += __shfl_xor(p, 1);
    p += __shfl_xor(p, 2);
    p += __shfl_xor(p, 4);              // full head dot in lanes 0..31 (8-lane groups)
    float pu = __shfl_xor(p, 32);       // broadcast to V half
    float sf = (lane >= 32) ? pu : p;
    float s = valid ? sf * scale : -1e30f;
    float e = __expf(s);                // no max-subtraction: |s| << 88
    sum += e;
    o0 += e * a0; o1 += e * a1; o2 += e * a2; o3 += e * a3;  // meaningful on V half
  }
  float inv = 1.f / sum;
  if (lane >= 32) {
    union { unsigned short s[4]; uint2 u; } p;
    p.s[0] = f2bf(o0 * inv); p.s[1] = f2bf(o1 * inv);
    p.s[2] = f2bf(o2 * inv); p.s[3] = f2bf(o3 * inv);
    *reinterpret_cast<uint2*>(&Ob[(size_t)n * 128 + 4 * l5]) = p.u;
  }
}

// ---------------- GEMM2: out = [O | x] @ [W2 | W00]^T + cvec ----------------
__global__ __launch_bounds__(256) void k_gemm_out(
    const unsigned short* __restrict__ Ob, const float* __restrict__ x,
    const unsigned short* __restrict__ W2cat, const float* __restrict__ cvec,
    float* __restrict__ out, int M) {
  __shared__ unsigned short sa[128 * LDK];
  __shared__ unsigned short sb[128 * LDK];
  const int m0 = blockIdx.x * 128;
  const int t = threadIdx.x;
  const int w = t >> 6, lane = t & 63, quad = lane >> 4, mr = lane & 15;

  f32x4 acc[2][8];
#pragma unroll
  for (int r = 0; r < 2; ++r)
#pragma unroll
    for (int c = 0; c < 8; ++c) acc[r][c] = (f32x4){0.f, 0.f, 0.f, 0.f};

  for (int kc = 0; kc < 4; ++kc) {
    if (kc < 2) {  // A-chunk from Ob (bf16)
#pragma unroll
      for (int i = 0; i < 4; ++i) {
        int ch = t + 256 * i;
        int row = ch >> 3, col8 = ch & 7;
        uint4 v = {0u, 0u, 0u, 0u};
        if (m0 + row < M)
          v = *reinterpret_cast<const uint4*>(&Ob[(size_t)(m0 + row) * 128 + kc * 64 + col8 * 8]);
        *reinterpret_cast<uint4*>(&sa[row * LDK + col8 * 8]) = v;
      }
    } else {       // A-chunk from x (fp32 -> bf16)
#pragma unroll
      for (int i = 0; i < 8; ++i) {
        int ch = t + 256 * i;
        int row = ch >> 4, col4 = ch & 15;
        float4 v = make_float4(0.f, 0.f, 0.f, 0.f);
        if (m0 + row < M)
          v = *reinterpret_cast<const float4*>(&x[(size_t)(m0 + row) * 128 + (kc - 2) * 64 + col4 * 4]);
        union { unsigned short s[4]; uint2 u; } p;
        p.s[0] = f2bf(v.x); p.s[1] = f2bf(v.y); p.s[2] = f2bf(v.z); p.s[3] = f2bf(v.w);
        *reinterpret_cast<uint2*>(&sa[row * LDK + col4 * 4]) = p.u;
      }
    }
#pragma unroll
    for (int i = 0; i < 4; ++i) {
      int ch = t + 256 * i;
      int row = ch >> 3, col8 = ch & 7;
      uint4 v = *reinterpret_cast<const uint4*>(&W2cat[(size_t)row * 256 + kc * 64 + col8 * 8]);
      *reinterpret_cast<uint4*>(&sb[row * LDK + col8 * 8]) = v;
    }
    __syncthreads();
#pragma unroll
    for (int ks = 0; ks < 2; ++ks) {
      int k0 = ks * 32 + quad * 8;
      bfrag a0 = *reinterpret_cast<const bfrag*>(&sa[(w * 32 + mr) * LDK + k0]);
      bfrag a1 = *reinterpret_cast<const bfrag*>(&sa[(w * 32 + 16 + mr) * LDK + k0]);
#pragma unroll
      for (int c = 0; c < 8; ++c) {
        bfrag b = *reinterpret_cast<const bfrag*>(&sb[(c * 16 + mr) * LDK + k0]);
        acc[0][c] = __builtin_amdgcn_mfma_f32_16x16x32_bf16(a0, b, acc[0][c], 0, 0, 0);
        acc[1][c] = __builtin_amdgcn_mfma_f32_16x16x32_bf16(a1, b, acc[1][c], 0, 0, 0);
      }
    }
    __syncthreads();
  }
#pragma unroll
  for (int r = 0; r < 2; ++r) {
    int rowbase = m0 + w * 32 + r * 16 + quad * 4;
#pragma unroll
    for (int c = 0; c < 8; ++c) {
      int col = c * 16 + mr;
      float cv = cvec[col];
#pragma unroll
      for (int g = 0; g < 4; ++g) {
        int row = rowbase + g;
        if (row < M) out[(size_t)row * 128 + col] = acc[r][c][g] + cv;
      }
    }
  }
}

extern "C" void kernel_launch(void* const* d_in, const int* in_sizes, int n_in,
                              void* d_out, int out_size, void* d_ws, size_t ws_size,
                              hipStream_t stream) {
  const float* x          = (const float*)d_in[0];
  const int*   fn         = (const int*)d_in[1];
  const float* in_proj_w  = (const float*)d_in[4];
  const float* in_proj_b  = (const float*)d_in[5];
  const float* out_proj_w = (const float*)d_in[6];
  const float* out_proj_b = (const float*)d_in[7];
  const float* conv_w     = (const float*)d_in[8];
  const float* conv_b     = (const float*)d_in[9];
  const int M = in_sizes[0] / 128;

  // KV (bf16, interleaved, 512B/row) fills d_out exactly; dead before GEMM2 writes out.
  unsigned short* KVb = (unsigned short*)d_out;
  char* ws = (char*)d_ws;
  unsigned short* Qb    = (unsigned short*)ws;
  unsigned short* Ob    = (unsigned short*)(ws + (size_t)M * 128 * 2);
  unsigned short* Wcat  = (unsigned short*)(ws + (size_t)M * 128 * 4);
  unsigned short* W2cat = Wcat + 384 * 128;
  float*          cvec  = (float*)(W2cat + 128 * 256);

  const int mt = (M + 127) / 128;
  k_prep<<<dim3(512), dim3(128), 0, stream>>>(in_proj_w, conv_w, out_proj_w,
                                              out_proj_b, conv_b, Wcat, W2cat, cvec);
  k_gemm_qkv<<<dim3(mt), dim3(256), 0, stream>>>(x, Wcat, in_proj_b, Qb, KVb, M);
  k_attn<<<dim3((M + 3) / 4), dim3(256), 0, stream>>>(Qb, KVb, fn, Ob, M);
  k_gemm_out<<<dim3(mt), dim3(256), 0, stream>>>(Ob, x, W2cat, cvec, (float*)d_out, M);
}

// Round 5
// 455.470 us; speedup vs baseline: 1.3396x; 1.0360x over previous
//
#include <hip/hip_runtime.h>

typedef __bf16 bfrag __attribute__((ext_vector_type(8)));
typedef float f32x4 __attribute__((ext_vector_type(4)));

__device__ __forceinline__ unsigned short f2bf(float f) {
  unsigned u = __float_as_uint(f);
  u = (u + 0x7fffu + ((u >> 16) & 1u)) >> 16;
  return (unsigned short)u;
}
__device__ __forceinline__ float bflo(unsigned u) {  // low 16 bits -> float
  return __uint_as_float(u << 16);
}
__device__ __forceinline__ float bfhi(unsigned u) {  // high 16 bits -> float
  return __uint_as_float(u & 0xffff0000u);
}

#define LDB 72  // B-tile row stride (ushort): 144B/row, 16B-aligned for b128 frag reads
#define LDE 76  // qkv epilogue stride (ushort): 4-row dword offset = 24 mod 32 -> no 4-way conflicts
#define LDO 36  // gemm_out epilogue stride (float): 144B/row, 16B-aligned float4 readback

// ---------------- weight prep ----------------
// Wcat rows 0..383 = in_proj_w (bf16)
// W2cat: 128 x 256: [W2 = conv_w01 @ out_proj_w | W00 = conv_w[:,:,0,0]]
// cvec = conv_b + conv_w01 @ out_proj_b
__global__ void k_prep(const float* __restrict__ in_proj_w,
                       const float* __restrict__ conv_w,
                       const float* __restrict__ out_proj_w,
                       const float* __restrict__ out_proj_b,
                       const float* __restrict__ conv_b,
                       unsigned short* __restrict__ Wcat,
                       unsigned short* __restrict__ W2cat,
                       float* __restrict__ cvec) {
  int b = blockIdx.x, t = threadIdx.x;
  if (b < 384) {
    Wcat[b * 128 + t] = f2bf(in_proj_w[b * 128 + t]);
  } else {
    int c = b - 384;
    float s = 0.f;
    for (int k = 0; k < 128; ++k)
      s += conv_w[(c * 128 + k) * 2 + 1] * out_proj_w[k * 128 + t];
    W2cat[c * 256 + t] = f2bf(s);
    W2cat[c * 256 + 128 + t] = f2bf(conv_w[(c * 128 + t) * 2]);
    if (t == 0) {
      float cs = conv_b[c];
      for (int k = 0; k < 128; ++k)
        cs += conv_w[(c * 128 + k) * 2 + 1] * out_proj_b[k];
      cvec[c] = cs;
    }
  }
}

// ---------------- fused QKV GEMM: A-fragments loaded DIRECT from global -----
// Q -> Qb (row=128 ushort). K,V -> KVb interleaved (row=256 ushort: K|V).
__global__ __launch_bounds__(256) void k_gemm_qkv(
    const float* __restrict__ x, const unsigned short* __restrict__ Wcat,
    const float* __restrict__ in_proj_b, unsigned short* __restrict__ Qb,
    unsigned short* __restrict__ KVb, int M) {
  __shared__ unsigned short sb[128 * LDB];  // 18.4 KB B staging
  __shared__ unsigned short se[128 * LDE];  // 19.5 KB epilogue transpose
  const int m0 = blockIdx.x * 128;
  const int t = threadIdx.x;
  const int w = t >> 6, lane = t & 63, quad = lane >> 4, mr = lane & 15;

  // A fragments straight from global: lane (quad,mr) needs rows w*32+r*16+mr,
  // cols ks*32+quad*8 .. +8  ->  2 x float4 + cvt per fragment. No LDS for A.
  bfrag af[4][2];
#pragma unroll
  for (int ks = 0; ks < 4; ++ks)
#pragma unroll
    for (int r = 0; r < 2; ++r) {
      int row = m0 + w * 32 + r * 16 + mr;
      union { unsigned short s[8]; bfrag f; } u;
      if (row < M) {
        const float4* p =
            reinterpret_cast<const float4*>(&x[(size_t)row * 128 + ks * 32 + quad * 8]);
        float4 v0 = p[0], v1 = p[1];
        u.s[0] = f2bf(v0.x); u.s[1] = f2bf(v0.y); u.s[2] = f2bf(v0.z); u.s[3] = f2bf(v0.w);
        u.s[4] = f2bf(v1.x); u.s[5] = f2bf(v1.y); u.s[6] = f2bf(v1.z); u.s[7] = f2bf(v1.w);
      } else {
#pragma unroll
        for (int i = 0; i < 8; ++i) u.s[i] = 0;
      }
      af[ks][r] = u.f;
    }

#pragma unroll
  for (int cb = 0; cb < 3; ++cb) {
    f32x4 acc[2][8];
#pragma unroll
    for (int r = 0; r < 2; ++r)
#pragma unroll
      for (int c = 0; c < 8; ++c) acc[r][c] = (f32x4){0.f, 0.f, 0.f, 0.f};

#pragma unroll
    for (int kh = 0; kh < 2; ++kh) {
      __syncthreads();  // sb free (prior mfma / prior cb done)
#pragma unroll
      for (int i = 0; i < 4; ++i) {
        int ch = t + 256 * i;  // 1024 chunks: 128 rows x 8 col8 (64 cols)
        int row = ch >> 3, col8 = ch & 7;
        uint4 v = *reinterpret_cast<const uint4*>(
            &Wcat[(size_t)(cb * 128 + row) * 128 + kh * 64 + col8 * 8]);
        *reinterpret_cast<uint4*>(&sb[row * LDB + col8 * 8]) = v;
      }
      __syncthreads();
#pragma unroll
      for (int ks2 = 0; ks2 < 2; ++ks2) {
        int ks = kh * 2 + ks2;
        int k0 = ks2 * 32 + quad * 8;
#pragma unroll
        for (int c = 0; c < 8; ++c) {
          bfrag b = *reinterpret_cast<const bfrag*>(&sb[(c * 16 + mr) * LDB + k0]);
          acc[0][c] = __builtin_amdgcn_mfma_f32_16x16x32_bf16(af[ks][0], b, acc[0][c], 0, 0, 0);
          acc[1][c] = __builtin_amdgcn_mfma_f32_16x16x32_bf16(af[ks][1], b, acc[1][c], 0, 0, 0);
        }
      }
    }
    // epilogue: 2 passes of 64 cols through se (conflict-free stride 76)
    const float* bias = in_proj_b + cb * 128;
    unsigned short* dst = (cb == 0) ? Qb : KVb;
    const int ldst = (cb == 0) ? 128 : 256;
    const int cb_off = (cb == 2) ? 128 : 0;
#pragma unroll
    for (int p = 0; p < 2; ++p) {
      __syncthreads();  // se free (previous pass / previous cb readback done)
#pragma unroll
      for (int r = 0; r < 2; ++r)
#pragma unroll
        for (int cc = 0; cc < 4; ++cc) {
          int c = p * 4 + cc;
          float bv = bias[c * 16 + mr];
#pragma unroll
          for (int g = 0; g < 4; ++g) {
            int row = w * 32 + r * 16 + quad * 4 + g;
            se[row * LDE + cc * 16 + mr] = f2bf(acc[r][c][g] + bv);
          }
        }
      __syncthreads();
#pragma unroll
      for (int i = 0; i < 4; ++i) {
        int ch = t + 256 * i;  // 1024 chunks: 128 rows x 8 col8 (64 cols)
        int row = ch >> 3, col8 = ch & 7;
        if (m0 + row < M) {
          uint2 lo = *reinterpret_cast<const uint2*>(&se[row * LDE + col8 * 8]);
          uint2 hi = *reinterpret_cast<const uint2*>(&se[row * LDE + col8 * 8 + 4]);
          uint4 v = {lo.x, lo.y, hi.x, hi.y};
          *reinterpret_cast<uint4*>(
              &dst[(size_t)(m0 + row) * ldst + cb_off + p * 64 + col8 * 8]) = v;
        }
      }
    }
  }
}

// ---------------- attention: 1 wave per row, interleaved KV gather ----------
// KV row = 512B: lanes 0..31 hold K ch 4*l5.., lanes 32..63 hold V ch 4*l5..
__global__ __launch_bounds__(256) void k_attn(
    const unsigned short* __restrict__ Qb, const unsigned short* __restrict__ KVb,
    const int* __restrict__ fn, unsigned short* __restrict__ Ob, int M) {
  int w = threadIdx.x >> 6, lane = threadIdx.x & 63;
  int n = blockIdx.x * 4 + w;
  if (n >= M) return;
  const float scale = 0.17677669529663687f;  // 1/sqrt(32)
  const int l5 = lane & 31;
  uint2 qp = *reinterpret_cast<const uint2*>(&Qb[(size_t)n * 128 + 4 * l5]);
  float q0 = bflo(qp.x), q1 = bfhi(qp.x), q2 = bflo(qp.y), q3 = bfhi(qp.y);
  int idx[8];
#pragma unroll
  for (int j = 0; j < 8; ++j) idx[j] = fn[n * 9 + 1 + j];
  float o0 = 0.f, o1 = 0.f, o2 = 0.f, o3 = 0.f, sum = 0.f;
#pragma unroll
  for (int j = 0; j < 8; ++j) {
    bool valid = idx[j] < M;
    int id = valid ? idx[j] : 0;
    uint2 kv = *reinterpret_cast<const uint2*>(&KVb[(size_t)id * 256 + 4 * lane]);
    float a0 = bflo(kv.x), a1 = bfhi(kv.x), a2 = bflo(kv.y), a3 = bfhi(kv.y);
    float p = q0 * a0 + q1 * a1 + q2 * a2 + q3 * a3;
    p += __shfl_xor(p, 1);
    p += __shfl_xor(p, 2);
    p += __shfl_xor(p, 4);              // full head dot in 8-lane groups of K half
    float pu = __shfl_xor(p, 32);       // broadcast to V half
    float sf = (lane >= 32) ? pu : p;
    float s = valid ? sf * scale : -1e30f;
    float e = __expf(s);                // no max-subtraction: |s| << 88
    sum += e;
    o0 += e * a0; o1 += e * a1; o2 += e * a2; o3 += e * a3;  // meaningful on V half
  }
  float inv = 1.f / sum;
  if (lane >= 32) {
    union { unsigned short s[4]; uint2 u; } p;
    p.s[0] = f2bf(o0 * inv); p.s[1] = f2bf(o1 * inv);
    p.s[2] = f2bf(o2 * inv); p.s[3] = f2bf(o3 * inv);
    *reinterpret_cast<uint2*>(&Ob[(size_t)n * 128 + 4 * l5]) = p.u;
  }
}

// ---------------- GEMM2: out = [O | x] @ [W2 | W00]^T + cvec ----------------
// A-fragments direct from global (Ob: uint4; x: 2 x float4 + cvt). LDS: B + epilogue.
__global__ __launch_bounds__(256) void k_gemm_out(
    const unsigned short* __restrict__ Ob, const float* __restrict__ x,
    const unsigned short* __restrict__ W2cat, const float* __restrict__ cvec,
    float* __restrict__ out, int M) {
  __shared__ unsigned short sb[128 * LDB];  // 18.4 KB
  __shared__ float sf[128 * LDO];           // 18.4 KB fp32 epilogue transpose
  const int m0 = blockIdx.x * 128;
  const int t = threadIdx.x;
  const int w = t >> 6, lane = t & 63, quad = lane >> 4, mr = lane & 15;

  f32x4 acc[2][8];
#pragma unroll
  for (int r = 0; r < 2; ++r)
#pragma unroll
    for (int c = 0; c < 8; ++c) acc[r][c] = (f32x4){0.f, 0.f, 0.f, 0.f};

#pragma unroll
  for (int kc = 0; kc < 4; ++kc) {
    // direct A fragments for this K-chunk
    bfrag af[2][2];
#pragma unroll
    for (int ks2 = 0; ks2 < 2; ++ks2)
#pragma unroll
      for (int r = 0; r < 2; ++r) {
        int row = m0 + w * 32 + r * 16 + mr;
        if (kc < 2) {
          union { uint4 v; bfrag f; } u;
          u.v = make_uint4(0u, 0u, 0u, 0u);
          if (row < M)
            u.v = *reinterpret_cast<const uint4*>(
                &Ob[(size_t)row * 128 + kc * 64 + ks2 * 32 + quad * 8]);
          af[ks2][r] = u.f;
        } else {
          union { unsigned short s[8]; bfrag f; } u;
          if (row < M) {
            const float4* p = reinterpret_cast<const float4*>(
                &x[(size_t)row * 128 + (kc - 2) * 64 + ks2 * 32 + quad * 8]);
            float4 v0 = p[0], v1 = p[1];
            u.s[0] = f2bf(v0.x); u.s[1] = f2bf(v0.y); u.s[2] = f2bf(v0.z); u.s[3] = f2bf(v0.w);
            u.s[4] = f2bf(v1.x); u.s[5] = f2bf(v1.y); u.s[6] = f2bf(v1.z); u.s[7] = f2bf(v1.w);
          } else {
#pragma unroll
            for (int i = 0; i < 8; ++i) u.s[i] = 0;
          }
          af[ks2][r] = u.f;
        }
      }
    __syncthreads();  // sb free
#pragma unroll
    for (int i = 0; i < 4; ++i) {
      int ch = t + 256 * i;
      int row = ch >> 3, col8 = ch & 7;
      uint4 v = *reinterpret_cast<const uint4*>(&W2cat[(size_t)row * 256 + kc * 64 + col8 * 8]);
      *reinterpret_cast<uint4*>(&sb[row * LDB + col8 * 8]) = v;
    }
    __syncthreads();
#pragma unroll
    for (int ks2 = 0; ks2 < 2; ++ks2) {
      int k0 = ks2 * 32 + quad * 8;
#pragma unroll
      for (int c = 0; c < 8; ++c) {
        bfrag b = *reinterpret_cast<const bfrag*>(&sb[(c * 16 + mr) * LDB + k0]);
        acc[0][c] = __builtin_amdgcn_mfma_f32_16x16x32_bf16(af[ks2][0], b, acc[0][c], 0, 0, 0);
        acc[1][c] = __builtin_amdgcn_mfma_f32_16x16x32_bf16(af[ks2][1], b, acc[1][c], 0, 0, 0);
      }
    }
  }
  // epilogue: 4 passes of 32 fp32 cols through sf -> coalesced float4 stores
#pragma unroll
  for (int p = 0; p < 4; ++p) {
    __syncthreads();
#pragma unroll
    for (int r = 0; r < 2; ++r)
#pragma unroll
      for (int cc = 0; cc < 2; ++cc) {
        int c = p * 2 + cc;
        float cv = cvec[c * 16 + mr];
#pragma unroll
        for (int g = 0; g < 4; ++g) {
          int row = w * 32 + r * 16 + quad * 4 + g;
          sf[row * LDO + cc * 16 + mr] = acc[r][c][g] + cv;
        }
      }
    __syncthreads();
#pragma unroll
    for (int i = 0; i < 4; ++i) {
      int ch = t + 256 * i;  // 1024 chunks: 128 rows x 8 col4 (32 cols)
      int row = ch >> 3, col4 = ch & 7;
      if (m0 + row < M) {
        float4 v = *reinterpret_cast<const float4*>(&sf[row * LDO + col4 * 4]);
        *reinterpret_cast<float4*>(&out[(size_t)(m0 + row) * 128 + p * 32 + col4 * 4]) = v;
      }
    }
  }
}

extern "C" void kernel_launch(void* const* d_in, const int* in_sizes, int n_in,
                              void* d_out, int out_size, void* d_ws, size_t ws_size,
                              hipStream_t stream) {
  const float* x          = (const float*)d_in[0];
  const int*   fn         = (const int*)d_in[1];
  const float* in_proj_w  = (const float*)d_in[4];
  const float* in_proj_b  = (const float*)d_in[5];
  const float* out_proj_w = (const float*)d_in[6];
  const float* out_proj_b = (const float*)d_in[7];
  const float* conv_w     = (const float*)d_in[8];
  const float* conv_b     = (const float*)d_in[9];
  const int M = in_sizes[0] / 128;

  // KV (bf16, interleaved, 512B/row) fills d_out exactly; dead before GEMM2 writes out.
  unsigned short* KVb = (unsigned short*)d_out;
  char* ws = (char*)d_ws;
  unsigned short* Qb    = (unsigned short*)ws;
  unsigned short* Ob    = (unsigned short*)(ws + (size_t)M * 128 * 2);
  unsigned short* Wcat  = (unsigned short*)(ws + (size_t)M * 128 * 4);
  unsigned short* W2cat = Wcat + 384 * 128;
  float*          cvec  = (float*)(W2cat + 128 * 256);

  const int mt = (M + 127) / 128;
  k_prep<<<dim3(512), dim3(128), 0, stream>>>(in_proj_w, conv_w, out_proj_w,
                                              out_proj_b, conv_b, Wcat, W2cat, cvec);
  k_gemm_qkv<<<dim3(mt), dim3(256), 0, stream>>>(x, Wcat, in_proj_b, Qb, KVb, M);
  k_attn<<<dim3((M + 3) / 4), dim3(256), 0, stream>>>(Qb, KVb, fn, Ob, M);
  k_gemm_out<<<dim3(mt), dim3(256), 0, stream>>>(Ob, x, W2cat, cvec, (float*)d_out, M);
}

// Round 6
// 441.055 us; speedup vs baseline: 1.3834x; 1.0327x over previous
//
#include <hip/hip_runtime.h>

typedef __bf16 bfrag __attribute__((ext_vector_type(8)));
typedef float f32x4 __attribute__((ext_vector_type(4)));

__device__ __forceinline__ unsigned short f2bf(float f) {
  unsigned u = __float_as_uint(f);
  u = (u + 0x7fffu + ((u >> 16) & 1u)) >> 16;
  return (unsigned short)u;
}
__device__ __forceinline__ float bflo(unsigned u) { return __uint_as_float(u << 16); }
__device__ __forceinline__ float bfhi(unsigned u) { return __uint_as_float(u & 0xffff0000u); }

// ---------------- weight prep: FRAGMENT-MAJOR layouts ----------------
// WcatF[((cb*8 + cB)*4 + ks)*512 + lane*8 + j]: B-frag for in_proj block cb,
//   col-block cB, k-step ks; lane=(quad*16+mr) holds row cB*16+mr, k=ks*32+quad*8+j.
// W2F[((cB*4 + kc)*2 + ks2)*512 + lane*8 + j]: same for [W2 | W00] (K=256).
// cvec = conv_b + conv_w01 @ out_proj_b
__global__ void k_prep(const float* __restrict__ in_proj_w,
                       const float* __restrict__ conv_w,
                       const float* __restrict__ out_proj_w,
                       const float* __restrict__ out_proj_b,
                       const float* __restrict__ conv_b,
                       unsigned short* __restrict__ WcatF,
                       unsigned short* __restrict__ W2F,
                       float* __restrict__ cvec) {
  int b = blockIdx.x, t = threadIdx.x;
  if (b < 384) {
    unsigned short v = f2bf(in_proj_w[b * 128 + t]);
    int cb = b >> 7, r7 = b & 127;
    int cB = r7 >> 4, mr = r7 & 15;
    int ks = t >> 5, quad = (t >> 3) & 3, j = t & 7;
    WcatF[(((cb * 8 + cB) * 4 + ks) << 9) + (quad * 16 + mr) * 8 + j] = v;
  } else {
    int c = b - 384;  // output channel (B-row)
    int cB = c >> 4, mr = c & 15;
    float s = 0.f;
    for (int k = 0; k < 128; ++k)
      s += conv_w[(c * 128 + k) * 2 + 1] * out_proj_w[k * 128 + t];
    {  // K = t (W2 part)
      int kc = t >> 6, ks2 = (t >> 5) & 1, quad = (t >> 3) & 3, j = t & 7;
      W2F[(((cB * 4 + kc) * 2 + ks2) << 9) + (quad * 16 + mr) * 8 + j] = f2bf(s);
    }
    {  // K = 128 + t (W00 part)
      int K = 128 + t;
      int kc = K >> 6, ks2 = (K >> 5) & 1, quad = (K >> 3) & 3, j = K & 7;
      W2F[(((cB * 4 + kc) * 2 + ks2) << 9) + (quad * 16 + mr) * 8 + j] =
          f2bf(conv_w[(c * 128 + t) * 2]);
    }
    if (t == 0) {
      float cs = conv_b[c];
      for (int k = 0; k < 128; ++k)
        cs += conv_w[(c * 128 + k) * 2 + 1] * out_proj_b[k];
      cvec[c] = cs;
    }
  }
}

// ---------------- fused QKV GEMM: ZERO barriers, all frags direct ----------
// Q -> Qb (row=128 ushort). K,V -> KVb interleaved (row=256 ushort: K|V).
__global__ __launch_bounds__(256, 4) void k_gemm_qkv(
    const float* __restrict__ x, const unsigned short* __restrict__ WcatF,
    const float* __restrict__ in_proj_b, unsigned short* __restrict__ Qb,
    unsigned short* __restrict__ KVb, int M) {
  __shared__ unsigned short se[4][32 * 72];  // wave-private transpose, 18.4 KB total
  const int m0 = blockIdx.x * 128;
  const int t = threadIdx.x;
  const int w = t >> 6, lane = t & 63, quad = lane >> 4, mr = lane & 15;
  unsigned short* sew = se[w];

  // A fragments direct from x: lane (quad,mr), rows w*32+r*16+mr, k=ks*32+quad*8
  bfrag af[4][2];
#pragma unroll
  for (int ks = 0; ks < 4; ++ks)
#pragma unroll
    for (int r = 0; r < 2; ++r) {
      int row = m0 + w * 32 + r * 16 + mr;
      union { unsigned short s[8]; bfrag f; } u;
      if (row < M) {
        const float4* p =
            reinterpret_cast<const float4*>(&x[(size_t)row * 128 + ks * 32 + quad * 8]);
        float4 v0 = p[0], v1 = p[1];
        u.s[0] = f2bf(v0.x); u.s[1] = f2bf(v0.y); u.s[2] = f2bf(v0.z); u.s[3] = f2bf(v0.w);
        u.s[4] = f2bf(v1.x); u.s[5] = f2bf(v1.y); u.s[6] = f2bf(v1.z); u.s[7] = f2bf(v1.w);
      } else {
#pragma unroll
        for (int i = 0; i < 8; ++i) u.s[i] = 0;
      }
      af[ks][r] = u.f;
    }

#pragma unroll
  for (int cb = 0; cb < 3; ++cb) {
    unsigned short* dst = (cb == 0) ? Qb : KVb;
    const int ldst = (cb == 0) ? 128 : 256;
    const int cb_off = (cb == 2) ? 128 : 0;
#pragma unroll
    for (int half = 0; half < 2; ++half) {
      f32x4 acc[2][4];
#pragma unroll
      for (int r = 0; r < 2; ++r)
#pragma unroll
        for (int c = 0; c < 4; ++c) acc[r][c] = (f32x4){0.f, 0.f, 0.f, 0.f};
#pragma unroll
      for (int ks = 0; ks < 4; ++ks)
#pragma unroll
        for (int c = 0; c < 4; ++c) {
          union { uint4 v; bfrag f; } u;
          u.v = *reinterpret_cast<const uint4*>(
              &WcatF[(((cb * 8 + half * 4 + c) * 4 + ks) << 9) + lane * 8]);
          acc[0][c] = __builtin_amdgcn_mfma_f32_16x16x32_bf16(af[ks][0], u.f, acc[0][c], 0, 0, 0);
          acc[1][c] = __builtin_amdgcn_mfma_f32_16x16x32_bf16(af[ks][1], u.f, acc[1][c], 0, 0, 0);
        }
      // wave-private epilogue: 32 rows x 64 cols -> bf16 -> coalesced stores
      const float* bias = in_proj_b + cb * 128 + half * 64;
#pragma unroll
      for (int r = 0; r < 2; ++r)
#pragma unroll
        for (int c = 0; c < 4; ++c) {
          float bv = bias[c * 16 + mr];
#pragma unroll
          for (int g = 0; g < 4; ++g)
            sew[(r * 16 + quad * 4 + g) * 72 + c * 16 + mr] = f2bf(acc[r][c][g] + bv);
        }
#pragma unroll
      for (int i = 0; i < 4; ++i) {
        int ch = i * 64 + lane;  // 256 chunks: 32 rows x 8 x 16B
        int row = ch >> 3, cp = ch & 7;
        int grow = m0 + w * 32 + row;
        if (grow < M) {
          uint4 v = *reinterpret_cast<const uint4*>(&sew[row * 72 + cp * 8]);
          *reinterpret_cast<uint4*>(
              &dst[(size_t)grow * ldst + cb_off + half * 64 + cp * 8]) = v;
        }
      }
    }
  }
}

// ---------------- attention: 1 wave per row, interleaved KV gather ----------
__global__ __launch_bounds__(256) void k_attn(
    const unsigned short* __restrict__ Qb, const unsigned short* __restrict__ KVb,
    const int* __restrict__ fn, unsigned short* __restrict__ Ob, int M) {
  int w = threadIdx.x >> 6, lane = threadIdx.x & 63;
  int n = blockIdx.x * 4 + w;
  if (n >= M) return;
  const float scale = 0.17677669529663687f;  // 1/sqrt(32)
  const int l5 = lane & 31;
  uint2 qp = *reinterpret_cast<const uint2*>(&Qb[(size_t)n * 128 + 4 * l5]);
  float q0 = bflo(qp.x), q1 = bfhi(qp.x), q2 = bflo(qp.y), q3 = bfhi(qp.y);
  int idx[8];
#pragma unroll
  for (int j = 0; j < 8; ++j) idx[j] = fn[n * 9 + 1 + j];
  float o0 = 0.f, o1 = 0.f, o2 = 0.f, o3 = 0.f, sum = 0.f;
#pragma unroll
  for (int j = 0; j < 8; ++j) {
    bool valid = idx[j] < M;
    int id = valid ? idx[j] : 0;
    uint2 kv = *reinterpret_cast<const uint2*>(&KVb[(size_t)id * 256 + 4 * lane]);
    float a0 = bflo(kv.x), a1 = bfhi(kv.x), a2 = bflo(kv.y), a3 = bfhi(kv.y);
    float p = q0 * a0 + q1 * a1 + q2 * a2 + q3 * a3;
    p += __shfl_xor(p, 1);
    p += __shfl_xor(p, 2);
    p += __shfl_xor(p, 4);              // full head dot in 8-lane groups of K half
    float pu = __shfl_xor(p, 32);       // broadcast to V half
    float sf = (lane >= 32) ? pu : p;
    float s = valid ? sf * scale : -1e30f;
    float e = __expf(s);                // |s| << 88, no max-pass needed
    sum += e;
    o0 += e * a0; o1 += e * a1; o2 += e * a2; o3 += e * a3;
  }
  float inv = 1.f / sum;
  if (lane >= 32) {
    union { unsigned short s[4]; uint2 u; } p;
    p.s[0] = f2bf(o0 * inv); p.s[1] = f2bf(o1 * inv);
    p.s[2] = f2bf(o2 * inv); p.s[3] = f2bf(o3 * inv);
    *reinterpret_cast<uint2*>(&Ob[(size_t)n * 128 + 4 * l5]) = p.u;
  }
}

// ---------------- GEMM2: out = [O | x] @ [W2 | W00]^T + cvec, ZERO barriers -
__global__ __launch_bounds__(256, 4) void k_gemm_out(
    const unsigned short* __restrict__ Ob, const float* __restrict__ x,
    const unsigned short* __restrict__ W2F, const float* __restrict__ cvec,
    float* __restrict__ out, int M) {
  __shared__ float sf[4][32 * 36];  // wave-private fp32 transpose, 18.4 KB total
  const int m0 = blockIdx.x * 128;
  const int t = threadIdx.x;
  const int w = t >> 6, lane = t & 63, quad = lane >> 4, mr = lane & 15;
  float* sfw = sf[w];

  f32x4 acc[2][8];
#pragma unroll
  for (int r = 0; r < 2; ++r)
#pragma unroll
    for (int c = 0; c < 8; ++c) acc[r][c] = (f32x4){0.f, 0.f, 0.f, 0.f};

#pragma unroll
  for (int kc = 0; kc < 4; ++kc) {
    bfrag af[2][2];  // A frags for this K-chunk, direct from global
#pragma unroll
    for (int ks2 = 0; ks2 < 2; ++ks2)
#pragma unroll
      for (int r = 0; r < 2; ++r) {
        int row = m0 + w * 32 + r * 16 + mr;
        if (kc < 2) {
          union { uint4 v; bfrag f; } u;
          u.v = make_uint4(0u, 0u, 0u, 0u);
          if (row < M)
            u.v = *reinterpret_cast<const uint4*>(
                &Ob[(size_t)row * 128 + kc * 64 + ks2 * 32 + quad * 8]);
          af[ks2][r] = u.f;
        } else {
          union { unsigned short s[8]; bfrag f; } u;
          if (row < M) {
            const float4* p = reinterpret_cast<const float4*>(
                &x[(size_t)row * 128 + (kc - 2) * 64 + ks2 * 32 + quad * 8]);
            float4 v0 = p[0], v1 = p[1];
            u.s[0] = f2bf(v0.x); u.s[1] = f2bf(v0.y); u.s[2] = f2bf(v0.z); u.s[3] = f2bf(v0.w);
            u.s[4] = f2bf(v1.x); u.s[5] = f2bf(v1.y); u.s[6] = f2bf(v1.z); u.s[7] = f2bf(v1.w);
          } else {
#pragma unroll
            for (int i = 0; i < 8; ++i) u.s[i] = 0;
          }
          af[ks2][r] = u.f;
        }
      }
#pragma unroll
    for (int ks2 = 0; ks2 < 2; ++ks2)
#pragma unroll
      for (int c = 0; c < 8; ++c) {
        union { uint4 v; bfrag f; } u;
        u.v = *reinterpret_cast<const uint4*>(
            &W2F[(((c * 4 + kc) * 2 + ks2) << 9) + lane * 8]);
        acc[0][c] = __builtin_amdgcn_mfma_f32_16x16x32_bf16(af[ks2][0], u.f, acc[0][c], 0, 0, 0);
        acc[1][c] = __builtin_amdgcn_mfma_f32_16x16x32_bf16(af[ks2][1], u.f, acc[1][c], 0, 0, 0);
      }
  }
  // wave-private epilogue: 4 passes of 32 fp32 cols
#pragma unroll
  for (int p = 0; p < 4; ++p) {
#pragma unroll
    for (int cc = 0; cc < 2; ++cc) {
      int c = p * 2 + cc;
      float cv = cvec[c * 16 + mr];
#pragma unroll
      for (int r = 0; r < 2; ++r)
#pragma unroll
        for (int g = 0; g < 4; ++g)
          sfw[(r * 16 + quad * 4 + g) * 36 + cc * 16 + mr] = acc[r][c][g] + cv;
    }
#pragma unroll
    for (int i = 0; i < 4; ++i) {
      int ch = i * 64 + lane;  // 256 chunks: 32 rows x 8 float4
      int row = ch >> 3, c4 = ch & 7;
      int grow = m0 + w * 32 + row;
      if (grow < M) {
        float4 v = *reinterpret_cast<const float4*>(&sfw[row * 36 + c4 * 4]);
        *reinterpret_cast<float4*>(&out[(size_t)grow * 128 + p * 32 + c4 * 4]) = v;
      }
    }
  }
}

extern "C" void kernel_launch(void* const* d_in, const int* in_sizes, int n_in,
                              void* d_out, int out_size, void* d_ws, size_t ws_size,
                              hipStream_t stream) {
  const float* x          = (const float*)d_in[0];
  const int*   fn         = (const int*)d_in[1];
  const float* in_proj_w  = (const float*)d_in[4];
  const float* in_proj_b  = (const float*)d_in[5];
  const float* out_proj_w = (const float*)d_in[6];
  const float* out_proj_b = (const float*)d_in[7];
  const float* conv_w     = (const float*)d_in[8];
  const float* conv_b     = (const float*)d_in[9];
  const int M = in_sizes[0] / 128;

  // KV (bf16, interleaved, 512B/row) fills d_out exactly; dead before GEMM2 writes out.
  unsigned short* KVb = (unsigned short*)d_out;
  char* ws = (char*)d_ws;
  unsigned short* Qb    = (unsigned short*)ws;
  unsigned short* Ob    = (unsigned short*)(ws + (size_t)M * 128 * 2);
  unsigned short* WcatF = (unsigned short*)(ws + (size_t)M * 128 * 4);
  unsigned short* W2F   = WcatF + 384 * 128;
  float*          cvec  = (float*)(W2F + 128 * 256);

  const int mt = (M + 127) / 128;
  k_prep<<<dim3(512), dim3(128), 0, stream>>>(in_proj_w, conv_w, out_proj_w,
                                              out_proj_b, conv_b, WcatF, W2F, cvec);
  k_gemm_qkv<<<dim3(mt), dim3(256), 0, stream>>>(x, WcatF, in_proj_b, Qb, KVb, M);
  k_attn<<<dim3((M + 3) / 4), dim3(256), 0, stream>>>(Qb, KVb, fn, Ob, M);
  k_gemm_out<<<dim3(mt), dim3(256), 0, stream>>>(Ob, x, W2F, cvec, (float*)d_out, M);
}